// Round 1
// baseline (1463.709 us; speedup 1.0000x reference)
//
#include <hip/hip_runtime.h>

#define NQ   100000
#define PP   8
#define CC   256
#define HIDN 256
#define HH   512
#define WW   512
#define DD   258
#define KK1  288      // layer-1 K padded to 9*32
#define KK2  256
#define TQ   16
#define XS_STRIDE 296 // bf16 elems per row (16B-aligned + 2-way-conflict-free for b128 frag reads)
#define HA_STRIDE 264 // bf16 elems per row (16B-aligned + 2-way-conflict-free)
#define HB_STRIDE 260 // f32 per row; 260 (not 264): saves 256B LDS -> 54272B/block -> 3 blocks/CU

typedef __attribute__((ext_vector_type(8))) __bf16 bf16x8;
typedef __attribute__((ext_vector_type(4))) float  f32x4;

__device__ __forceinline__ unsigned short f2bf_hi(float v, float* rem) {
    __bf16 h = (__bf16)v;
    *rem = v - (float)h;
    return __builtin_bit_cast(unsigned short, h);
}
__device__ __forceinline__ unsigned short f2bf(float v) {
    __bf16 h = (__bf16)v;
    return __builtin_bit_cast(unsigned short, h);
}

// ---------------- ws layout (bytes) ----------------
// W1TH: [br][n=256][k=288] bf16   @ 0        (294912)
// W1TL:                           @ 294912   (294912)
// W2TH: [br][n=256][k=256] bf16   @ 589824   (262144)
// W2TL:                           @ 851968   (262144)
// W3T : [24][256] f32 (16 off cols, 8 wgt)   @ 1114112 (24576)
// B1E : [br][256] f32             @ 1138688  (2048)
#define WS_W1TH 0
#define WS_W1TL 294912
#define WS_W2TH 589824
#define WS_W2TL 851968
#define WS_W3T  1114112
#define WS_B1E  1138688

// ---------------------------------------------------------------------------
// prep: fold LN affine into W1, transpose + zero-pad + bf16 hi/lo split
// ---------------------------------------------------------------------------
__global__ void prep_w1(const float* __restrict__ og, const float* __restrict__ obl,
                        const float* __restrict__ oW1, const float* __restrict__ ob1,
                        const float* __restrict__ wg, const float* __restrict__ wbl,
                        const float* __restrict__ wW1, const float* __restrict__ wb1,
                        unsigned short* __restrict__ w1th, unsigned short* __restrict__ w1tl,
                        float* __restrict__ b1e) {
    const int br = blockIdx.y, k = blockIdx.x, n = threadIdx.x;
    const float* g  = br ? wg  : og;
    const float* bl = br ? wbl : obl;
    const float* W1 = br ? wW1 : oW1;
    const float* b1 = br ? wb1 : ob1;
    float v = (k < DD) ? g[k] * W1[k * HIDN + n] : 0.f;
    float rem; unsigned short hi = f2bf_hi(v, &rem);
    size_t o = (size_t)br * 256 * KK1 + (size_t)n * KK1 + k;
    w1th[o] = hi; w1tl[o] = f2bf(rem);
    if (k == 0) {
        float s = b1[n];
        for (int kk = 0; kk < DD; ++kk) s += bl[kk] * W1[kk * HIDN + n];
        b1e[br * 256 + n] = s;
    }
}

__global__ void prep_w2(const float* __restrict__ oW2, const float* __restrict__ wW2,
                        unsigned short* __restrict__ w2th, unsigned short* __restrict__ w2tl) {
    const int br = blockIdx.y, k = blockIdx.x, n = threadIdx.x;
    const float* W2 = br ? wW2 : oW2;
    float v = W2[k * HIDN + n];
    float rem; unsigned short hi = f2bf_hi(v, &rem);
    size_t o = (size_t)br * 256 * KK2 + (size_t)n * KK2 + k;
    w2th[o] = hi; w2tl[o] = f2bf(rem);
}

__global__ void prep_w3(const float* __restrict__ oW3, const float* __restrict__ wW3,
                        float* __restrict__ w3t) {
    const int br = blockIdx.x, t = threadIdx.x;
    if (br == 0) {
        const int c = t & 15, kb = t >> 4;
        for (int i = 0; i < 16; ++i) { int k = kb * 16 + i; w3t[c * 256 + k] = oW3[k * 16 + c]; }
    } else {
        const int c = t & 7, kb = t >> 3;
        for (int i = 0; i < 8; ++i)  { int k = kb * 8 + i;  w3t[(16 + c) * 256 + k] = wW3[k * 8 + c]; }
    }
}

// ---------------------------------------------------------------------------
// fused: LN -> (MFMA split-bf16 L1,L2 + fp32 L3) x2 -> softmax/tanh -> gather
// ---------------------------------------------------------------------------
__launch_bounds__(256, 3)
__global__ void fused_kernel(const float* __restrict__ gq, const float* __restrict__ pc,
                             const float* __restrict__ fmap,
                             const unsigned short* __restrict__ w1th, const unsigned short* __restrict__ w1tl,
                             const unsigned short* __restrict__ w2th, const unsigned short* __restrict__ w2tl,
                             const float* __restrict__ w3t, const float* __restrict__ b1e,
                             const float* __restrict__ ob2, const float* __restrict__ ob3,
                             const float* __restrict__ wb2, const float* __restrict__ wb3,
                             float* __restrict__ out) {
    __shared__ __align__(16) unsigned short xsh[TQ * XS_STRIDE];
    __shared__ __align__(16) unsigned short xsl[TQ * XS_STRIDE];
    __shared__ __align__(16) unsigned short hah[TQ * HA_STRIDE];
    __shared__ __align__(16) unsigned short hal[TQ * HA_STRIDE];
    __shared__ __align__(16) float hb[TQ * HB_STRIDE];
    __shared__ __align__(16) float raw[TQ * 24];
    __shared__ __align__(16) float pcs[TQ * 2];

    const int t    = threadIdx.x;
    const int q0   = blockIdx.x * TQ;
    const int lane = t & 63;
    const int wv   = t >> 6;
    const int quad = lane >> 4;
    const int l15  = lane & 15;

    // ---- zero xs pad regions; stage x (f32) into hb; coords ----
    for (int i = t; i < TQ * XS_STRIDE / 2; i += 256) {
        ((unsigned int*)xsh)[i] = 0u; ((unsigned int*)xsl)[i] = 0u;
    }
    for (int q = 0; q < TQ; ++q)
        hb[q * HB_STRIDE + t] = gq[(size_t)(q0 + q) * CC + t];
    if (t < TQ * 2) {
        float v = pc[(size_t)q0 * 2 + t];
        pcs[t] = v;
        hb[(t >> 1) * HB_STRIDE + CC + (t & 1)] = v;
    }
    __syncthreads();

    // ---- layernorm -> xs hi/lo (affine folded into W1/b1eff) ----
    for (int qi = 0; qi < TQ; qi += 4) {
        const int q = qi + wv;
        float s = 0.f, ss = 0.f;
        for (int k = lane; k < DD; k += 64) {
            float v = hb[q * HB_STRIDE + k]; s += v; ss += v * v;
        }
        for (int off = 32; off > 0; off >>= 1) {
            s += __shfl_xor(s, off, 64); ss += __shfl_xor(ss, off, 64);
        }
        const float mu = s * (1.f / DD);
        const float var = fmaxf(ss * (1.f / DD) - mu * mu, 0.f);
        const float rs = rsqrtf(var + 1e-5f);
        for (int k = lane; k < DD; k += 64) {
            float v = (hb[q * HB_STRIDE + k] - mu) * rs;
            float rem; xsh[q * XS_STRIDE + k] = f2bf_hi(v, &rem);
            xsl[q * XS_STRIDE + k] = f2bf(rem);
        }
    }
    __syncthreads();

    for (int br = 0; br < 2; ++br) {
        // ---- layer 1: hA = relu(x @ W1eff + b1eff), MFMA 16x16x32 split-bf16 ----
        {
            f32x4 acc[4];
            #pragma unroll
            for (int nt = 0; nt < 4; ++nt) {
                float b = b1e[br * 256 + wv * 64 + nt * 16 + l15];
                acc[nt] = (f32x4){b, b, b, b};
            }
            const unsigned short* Wh = w1th + (size_t)br * 256 * KK1;
            const unsigned short* Wl = w1tl + (size_t)br * 256 * KK1;
            const unsigned short* axh = xsh + l15 * XS_STRIDE + quad * 8;
            const unsigned short* axl = xsl + l15 * XS_STRIDE + quad * 8;
            for (int k0 = 0; k0 < KK1; k0 += 32) {
                const bf16x8 ah = *(const bf16x8*)(axh + k0);
                const bf16x8 al = *(const bf16x8*)(axl + k0);
                #pragma unroll
                for (int nt = 0; nt < 4; ++nt) {
                    const size_t n = wv * 64 + nt * 16 + l15;
                    const bf16x8 bh = *(const bf16x8*)(Wh + n * KK1 + k0 + quad * 8);
                    const bf16x8 bl = *(const bf16x8*)(Wl + n * KK1 + k0 + quad * 8);
                    acc[nt] = __builtin_amdgcn_mfma_f32_16x16x32_bf16(ah, bh, acc[nt], 0, 0, 0);
                    acc[nt] = __builtin_amdgcn_mfma_f32_16x16x32_bf16(ah, bl, acc[nt], 0, 0, 0);
                    acc[nt] = __builtin_amdgcn_mfma_f32_16x16x32_bf16(al, bh, acc[nt], 0, 0, 0);
                }
            }
            #pragma unroll
            for (int nt = 0; nt < 4; ++nt) {
                const int n = wv * 64 + nt * 16 + l15;
                #pragma unroll
                for (int r = 0; r < 4; ++r) {
                    const int m = quad * 4 + r;
                    float v = fmaxf(acc[nt][r], 0.f);
                    float rem; hah[m * HA_STRIDE + n] = f2bf_hi(v, &rem);
                    hal[m * HA_STRIDE + n] = f2bf(rem);
                }
            }
        }
        __syncthreads();

        // ---- layer 2: hb = relu(hA @ W2 + b2), MFMA split-bf16 ----
        {
            const float* b2 = br ? wb2 : ob2;
            f32x4 acc[4];
            #pragma unroll
            for (int nt = 0; nt < 4; ++nt) {
                float b = b2[wv * 64 + nt * 16 + l15];
                acc[nt] = (f32x4){b, b, b, b};
            }
            const unsigned short* Wh = w2th + (size_t)br * 256 * KK2;
            const unsigned short* Wl = w2tl + (size_t)br * 256 * KK2;
            const unsigned short* axh = hah + l15 * HA_STRIDE + quad * 8;
            const unsigned short* axl = hal + l15 * HA_STRIDE + quad * 8;
            for (int k0 = 0; k0 < KK2; k0 += 32) {
                const bf16x8 ah = *(const bf16x8*)(axh + k0);
                const bf16x8 al = *(const bf16x8*)(axl + k0);
                #pragma unroll
                for (int nt = 0; nt < 4; ++nt) {
                    const size_t n = wv * 64 + nt * 16 + l15;
                    const bf16x8 bh = *(const bf16x8*)(Wh + n * KK2 + k0 + quad * 8);
                    const bf16x8 bl = *(const bf16x8*)(Wl + n * KK2 + k0 + quad * 8);
                    acc[nt] = __builtin_amdgcn_mfma_f32_16x16x32_bf16(ah, bh, acc[nt], 0, 0, 0);
                    acc[nt] = __builtin_amdgcn_mfma_f32_16x16x32_bf16(ah, bl, acc[nt], 0, 0, 0);
                    acc[nt] = __builtin_amdgcn_mfma_f32_16x16x32_bf16(al, bh, acc[nt], 0, 0, 0);
                }
            }
            #pragma unroll
            for (int nt = 0; nt < 4; ++nt) {
                const int n = wv * 64 + nt * 16 + l15;
                #pragma unroll
                for (int r = 0; r < 4; ++r) {
                    const int m = quad * 4 + r;
                    hb[m * HB_STRIDE + n] = fmaxf(acc[nt][r], 0.f);
                }
            }
        }
        __syncthreads();

        // ---- layer 3 (fp32, transposed W3, float4 k-loop) ----
        if (br == 0) {
            const int q = t >> 4, c = t & 15;
            float s = ob3[c];
            const float4* wv4 = (const float4*)(w3t + c * 256);
            const float4* hv4 = (const float4*)(hb + q * HB_STRIDE);
            for (int k4 = 0; k4 < 64; ++k4) {
                float4 h = hv4[k4], w = wv4[k4];
                s += h.x * w.x + h.y * w.y + h.z * w.z + h.w * w.w;
            }
            raw[q * 24 + c] = s;
        } else if (t < TQ * 8) {
            const int q = t >> 3, c = t & 7;
            float s = wb3[c];
            const float4* wv4 = (const float4*)(w3t + (16 + c) * 256);
            const float4* hv4 = (const float4*)(hb + q * HB_STRIDE);
            for (int k4 = 0; k4 < 64; ++k4) {
                float4 h = hv4[k4], w = wv4[k4];
                s += h.x * w.x + h.y * w.y + h.z * w.z + h.w * w.w;
            }
            raw[q * 24 + 16 + c] = s;
        }
        __syncthreads();
    }

    // ---- epilogue: tanh, softmax, bilinear indices+weights (alias dead xs) ----
    int*   sidx = (int*)xsh;         // [TQ][8][4]
    float* sw   = (float*)xsl;       // [TQ][8][4]
    if (t < TQ) {
        const int q = t;
        float m = -1e30f;
        #pragma unroll
        for (int p = 0; p < 8; ++p) m = fmaxf(m, raw[q * 24 + 16 + p]);
        float e[8]; float S = 0.f;
        #pragma unroll
        for (int p = 0; p < 8; ++p) { e[p] = expf(raw[q * 24 + 16 + p] - m); S += e[p]; }
        float s2 = 0.f;
        #pragma unroll
        for (int p = 0; p < 8; ++p) { e[p] /= S; s2 += e[p]; }
        const float inv = 1.f / fmaxf(s2, 1e-8f);

        const float px = pcs[q * 2 + 0], py = pcs[q * 2 + 1];
        #pragma unroll
        for (int p = 0; p < 8; ++p) {
            const float cx = px + 2.f * tanhf(raw[q * 24 + 2 * p]);
            const float cy = py + 2.f * tanhf(raw[q * 24 + 2 * p + 1]);
            const float gx = fminf(fmaxf(2.f * cx * (1.f / (WW - 1)) - 1.f, -1.1f), 1.1f);
            const float gy = fminf(fmaxf(2.f * cy * (1.f / (HH - 1)) - 1.f, -1.1f), 1.1f);
            const float ix = fminf(fmaxf((gx + 1.f) * 0.5f * (WW - 1), 0.f), (float)(WW - 1));
            const float iy = fminf(fmaxf((gy + 1.f) * 0.5f * (HH - 1), 0.f), (float)(HH - 1));
            const float x0 = floorf(ix), y0 = floorf(iy);
            const float wx = ix - x0, wy = iy - y0;
            const int x0i = (int)x0, y0i = (int)y0;
            const int x1i = min(x0i + 1, WW - 1), y1i = min(y0i + 1, HH - 1);
            const float nwp = e[p] * inv;
            const int b = (q * 8 + p) * 4;
            sidx[b + 0] = (y0i * WW + x0i) * (CC / 4);
            sidx[b + 1] = (y0i * WW + x1i) * (CC / 4);
            sidx[b + 2] = (y1i * WW + x0i) * (CC / 4);
            sidx[b + 3] = (y1i * WW + x1i) * (CC / 4);
            sw[b + 0] = (1.f - wx) * (1.f - wy) * nwp;
            sw[b + 1] = wx * (1.f - wy) * nwp;
            sw[b + 2] = (1.f - wx) * wy * nwp;
            sw[b + 3] = wx * wy * nwp;
        }
    }
    __syncthreads();

    // ---- gather + weighted sum ----
    const float4* fm4 = (const float4*)fmap;
    float4* out4 = (float4*)out;
    #pragma unroll
    for (int qq = 0; qq < 4; ++qq) {
        const int q = wv * 4 + qq;
        float4 acc; acc.x = acc.y = acc.z = acc.w = 0.f;
        for (int p = 0; p < 8; ++p) {
            const int b = (q * 8 + p) * 4;
            const int i00 = sidx[b + 0] + lane;
            const int i01 = sidx[b + 1] + lane;
            const int i10 = sidx[b + 2] + lane;
            const int i11 = sidx[b + 3] + lane;
            const float a00 = sw[b + 0], a01 = sw[b + 1], a10 = sw[b + 2], a11 = sw[b + 3];
            const float4 v00 = fm4[i00], v01 = fm4[i01], v10 = fm4[i10], v11 = fm4[i11];
            acc.x += a00 * v00.x + a01 * v01.x + a10 * v10.x + a11 * v11.x;
            acc.y += a00 * v00.y + a01 * v01.y + a10 * v10.y + a11 * v11.y;
            acc.z += a00 * v00.z + a01 * v01.z + a10 * v10.z + a11 * v11.z;
            acc.w += a00 * v00.w + a01 * v01.w + a10 * v10.w + a11 * v11.w;
        }
        out4[(size_t)(q0 + q) * (CC / 4) + lane] = acc;
    }
}

extern "C" void kernel_launch(void* const* d_in, const int* in_sizes, int n_in,
                              void* d_out, int out_size, void* d_ws, size_t ws_size,
                              hipStream_t stream) {
    const float* gq   = (const float*)d_in[0];
    const float* pc   = (const float*)d_in[1];
    const float* fmap = (const float*)d_in[2];
    const float* og   = (const float*)d_in[3];
    const float* obl  = (const float*)d_in[4];
    const float* oW1  = (const float*)d_in[5];
    const float* ob1  = (const float*)d_in[6];
    const float* oW2  = (const float*)d_in[7];
    const float* ob2  = (const float*)d_in[8];
    const float* oW3  = (const float*)d_in[9];
    const float* ob3  = (const float*)d_in[10];
    const float* wg   = (const float*)d_in[11];
    const float* wbl  = (const float*)d_in[12];
    const float* wW1  = (const float*)d_in[13];
    const float* wb1  = (const float*)d_in[14];
    const float* wW2  = (const float*)d_in[15];
    const float* wb2  = (const float*)d_in[16];
    const float* wW3  = (const float*)d_in[17];
    const float* wb3  = (const float*)d_in[18];

    char* ws = (char*)d_ws;
    unsigned short* w1th = (unsigned short*)(ws + WS_W1TH);
    unsigned short* w1tl = (unsigned short*)(ws + WS_W1TL);
    unsigned short* w2th = (unsigned short*)(ws + WS_W2TH);
    unsigned short* w2tl = (unsigned short*)(ws + WS_W2TL);
    float* w3t = (float*)(ws + WS_W3T);
    float* b1e = (float*)(ws + WS_B1E);
    float* out = (float*)d_out;

    prep_w1<<<dim3(KK1, 2), 256, 0, stream>>>(og, obl, oW1, ob1, wg, wbl, wW1, wb1, w1th, w1tl, b1e);
    prep_w2<<<dim3(KK2, 2), 256, 0, stream>>>(oW2, wW2, w2th, w2tl);
    prep_w3<<<2, 256, 0, stream>>>(oW3, wW3, w3t);
    fused_kernel<<<NQ / TQ, 256, 0, stream>>>(gq, pc, fmap, w1th, w1tl, w2th, w2tl, w3t, b1e,
                                              ob2, ob3, wb2, wb3, out);
}

// Round 2
// 1197.212 us; speedup vs baseline: 1.2226x; 1.2226x over previous
//
#include <hip/hip_runtime.h>

#define NQ   100000
#define PP   8
#define CC   256
#define HIDN 256
#define HH   512
#define WW   512
#define DD   258
#define KK1  288      // layer-1 K padded to 9*32
#define KK2  256
#define TQ   32       // queries per block
#define NTHR 512      // 8 waves: each owns a 32-col n-slice x 2 m-tiles
#define XS_STRIDE 296 // bf16 elems per row (16B-aligned + 2-way-conflict-free for b128 frag reads)

typedef __attribute__((ext_vector_type(8))) __bf16 bf16x8;
typedef __attribute__((ext_vector_type(4))) float  f32x4;
typedef __attribute__((ext_vector_type(4))) unsigned short u16x4;
typedef __attribute__((ext_vector_type(8))) unsigned short u16x8;

__device__ __forceinline__ unsigned short f2bf_hi(float v, float* rem) {
    __bf16 h = (__bf16)v;
    *rem = v - (float)h;
    return __builtin_bit_cast(unsigned short, h);
}
__device__ __forceinline__ unsigned short f2bf(float v) {
    __bf16 h = (__bf16)v;
    return __builtin_bit_cast(unsigned short, h);
}
__device__ __forceinline__ float bf2f(unsigned short h) {
    unsigned int u = ((unsigned int)h) << 16;
    return __builtin_bit_cast(float, u);
}

// ---------------- ws layout (bytes) ----------------
#define WS_W1TH 0
#define WS_W1TL 294912
#define WS_W2TH 589824
#define WS_W2TL 851968
#define WS_W3T  1114112
#define WS_B1E  1138688

// ---------------------------------------------------------------------------
// prep: fold LN affine into W1, transpose + zero-pad + bf16 hi/lo split
// ---------------------------------------------------------------------------
__global__ void prep_w1(const float* __restrict__ og, const float* __restrict__ obl,
                        const float* __restrict__ oW1, const float* __restrict__ ob1,
                        const float* __restrict__ wg, const float* __restrict__ wbl,
                        const float* __restrict__ wW1, const float* __restrict__ wb1,
                        unsigned short* __restrict__ w1th, unsigned short* __restrict__ w1tl,
                        float* __restrict__ b1e) {
    const int br = blockIdx.y, k = blockIdx.x, n = threadIdx.x;
    const float* g  = br ? wg  : og;
    const float* bl = br ? wbl : obl;
    const float* W1 = br ? wW1 : oW1;
    const float* b1 = br ? wb1 : ob1;
    float v = (k < DD) ? g[k] * W1[k * HIDN + n] : 0.f;
    float rem; unsigned short hi = f2bf_hi(v, &rem);
    size_t o = (size_t)br * 256 * KK1 + (size_t)n * KK1 + k;
    w1th[o] = hi; w1tl[o] = f2bf(rem);
    if (k == 0) {
        float s = b1[n];
        for (int kk = 0; kk < DD; ++kk) s += bl[kk] * W1[kk * HIDN + n];
        b1e[br * 256 + n] = s;
    }
}

__global__ void prep_w2(const float* __restrict__ oW2, const float* __restrict__ wW2,
                        unsigned short* __restrict__ w2th, unsigned short* __restrict__ w2tl) {
    const int br = blockIdx.y, k = blockIdx.x, n = threadIdx.x;
    const float* W2 = br ? wW2 : oW2;
    float v = W2[k * HIDN + n];
    float rem; unsigned short hi = f2bf_hi(v, &rem);
    size_t o = (size_t)br * 256 * KK2 + (size_t)n * KK2 + k;
    w2th[o] = hi; w2tl[o] = f2bf(rem);
}

__global__ void prep_w3(const float* __restrict__ oW3, const float* __restrict__ wW3,
                        float* __restrict__ w3t) {
    const int br = blockIdx.x, t = threadIdx.x;
    if (br == 0) {
        const int c = t & 15, kb = t >> 4;
        for (int i = 0; i < 16; ++i) { int k = kb * 16 + i; w3t[c * 256 + k] = oW3[k * 16 + c]; }
    } else {
        const int c = t & 7, kb = t >> 3;
        for (int i = 0; i < 8; ++i)  { int k = kb * 8 + i;  w3t[(16 + c) * 256 + k] = wW3[k * 8 + c]; }
    }
}

// ---------------------------------------------------------------------------
// fused: reg-LN -> (MFMA split-bf16 L1,L2 + L3) x2 -> softmax/tanh -> gather
// xs buffer is reused: x -> hA -> h2 per branch (LN recomputed per branch).
// LDS = 41472 B -> 2-3 blocks/CU of 8 waves.
// ---------------------------------------------------------------------------
__launch_bounds__(NTHR, 4)
__global__ void fused_kernel(const float* __restrict__ gq, const float* __restrict__ pc,
                             const float* __restrict__ fmap,
                             const unsigned short* __restrict__ w1th, const unsigned short* __restrict__ w1tl,
                             const unsigned short* __restrict__ w2th, const unsigned short* __restrict__ w2tl,
                             const float* __restrict__ w3t, const float* __restrict__ b1e,
                             const float* __restrict__ ob2, const float* __restrict__ ob3,
                             const float* __restrict__ wb2, const float* __restrict__ wb3,
                             float* __restrict__ out) {
    __shared__ __align__(16) unsigned short xsh[TQ * XS_STRIDE];
    __shared__ __align__(16) unsigned short xsl[TQ * XS_STRIDE];
    __shared__ __align__(16) float raw[TQ * 24];
    __shared__ __align__(16) float pcs[TQ * 2];

    const int t    = threadIdx.x;
    const int q0   = blockIdx.x * TQ;
    const int lane = t & 63;
    const int wv   = t >> 6;       // 0..7
    const int quad = lane >> 4;
    const int l15  = lane & 15;

    // ---- zero xs (pad regions must be 0); stage coords ----
    for (int i = t; i < TQ * XS_STRIDE / 2; i += NTHR) {
        ((unsigned int*)xsh)[i] = 0u; ((unsigned int*)xsl)[i] = 0u;
    }
    if (t < TQ * 2) pcs[t] = pc[(size_t)q0 * 2 + t];
    __syncthreads();

    const float4* gq4 = (const float4*)gq;

    for (int br = 0; br < 2; ++br) {
        // ---- layernorm from registers -> xs hi/lo (affine folded into W1/b1eff) ----
        #pragma unroll
        for (int qq = 0; qq < 4; ++qq) {
            const int q = wv * 4 + qq;
            const float4 v = gq4[(size_t)(q0 + q) * 64 + lane];
            const float px = pcs[q * 2 + 0], py = pcs[q * 2 + 1];
            float s  = v.x + v.y + v.z + v.w;
            float ss = v.x * v.x + v.y * v.y + v.z * v.z + v.w * v.w;
            if (lane == 0) { s += px + py; ss += px * px + py * py; }
            #pragma unroll
            for (int off = 32; off > 0; off >>= 1) {
                s += __shfl_xor(s, off, 64); ss += __shfl_xor(ss, off, 64);
            }
            const float mu = s * (1.f / DD);
            const float var = fmaxf(ss * (1.f / DD) - mu * mu, 0.f);
            const float rs = rsqrtf(var + 1e-5f);
            const float n0 = (v.x - mu) * rs, n1 = (v.y - mu) * rs;
            const float n2 = (v.z - mu) * rs, n3 = (v.w - mu) * rs;
            float r0, r1, r2, r3;
            u16x4 hh; u16x4 ll;
            hh[0] = f2bf_hi(n0, &r0); hh[1] = f2bf_hi(n1, &r1);
            hh[2] = f2bf_hi(n2, &r2); hh[3] = f2bf_hi(n3, &r3);
            ll[0] = f2bf(r0); ll[1] = f2bf(r1); ll[2] = f2bf(r2); ll[3] = f2bf(r3);
            *(u16x4*)(&xsh[q * XS_STRIDE + lane * 4]) = hh;
            *(u16x4*)(&xsl[q * XS_STRIDE + lane * 4]) = ll;
            if (lane == 0) {
                const float nx = (px - mu) * rs, ny = (py - mu) * rs;
                float rx, ry;
                xsh[q * XS_STRIDE + 256] = f2bf_hi(nx, &rx);
                xsh[q * XS_STRIDE + 257] = f2bf_hi(ny, &ry);
                xsl[q * XS_STRIDE + 256] = f2bf(rx);
                xsl[q * XS_STRIDE + 257] = f2bf(ry);
            }
        }
        __syncthreads();

        // ---- layer 1: hA = relu(x @ W1eff + b1eff) ----
        {
            f32x4 acc[2][2];
            #pragma unroll
            for (int mt = 0; mt < 2; ++mt)
                #pragma unroll
                for (int nt = 0; nt < 2; ++nt) {
                    float b = b1e[br * 256 + wv * 32 + nt * 16 + l15];
                    acc[mt][nt] = (f32x4){b, b, b, b};
                }
            const unsigned short* Wh = w1th + (size_t)br * 256 * KK1;
            const unsigned short* Wl = w1tl + (size_t)br * 256 * KK1;
            const unsigned short* a0h = xsh + l15 * XS_STRIDE + quad * 8;
            const unsigned short* a0l = xsl + l15 * XS_STRIDE + quad * 8;
            const unsigned short* a1h = a0h + 16 * XS_STRIDE;
            const unsigned short* a1l = a0l + 16 * XS_STRIDE;
            for (int k0 = 0; k0 < KK1; k0 += 32) {
                const bf16x8 ah0 = *(const bf16x8*)(a0h + k0);
                const bf16x8 al0 = *(const bf16x8*)(a0l + k0);
                const bf16x8 ah1 = *(const bf16x8*)(a1h + k0);
                const bf16x8 al1 = *(const bf16x8*)(a1l + k0);
                #pragma unroll
                for (int nt = 0; nt < 2; ++nt) {
                    const size_t n = wv * 32 + nt * 16 + l15;
                    const bf16x8 bh = *(const bf16x8*)(Wh + n * KK1 + k0 + quad * 8);
                    const bf16x8 bl = *(const bf16x8*)(Wl + n * KK1 + k0 + quad * 8);
                    acc[0][nt] = __builtin_amdgcn_mfma_f32_16x16x32_bf16(ah0, bh, acc[0][nt], 0, 0, 0);
                    acc[0][nt] = __builtin_amdgcn_mfma_f32_16x16x32_bf16(ah0, bl, acc[0][nt], 0, 0, 0);
                    acc[0][nt] = __builtin_amdgcn_mfma_f32_16x16x32_bf16(al0, bh, acc[0][nt], 0, 0, 0);
                    acc[1][nt] = __builtin_amdgcn_mfma_f32_16x16x32_bf16(ah1, bh, acc[1][nt], 0, 0, 0);
                    acc[1][nt] = __builtin_amdgcn_mfma_f32_16x16x32_bf16(ah1, bl, acc[1][nt], 0, 0, 0);
                    acc[1][nt] = __builtin_amdgcn_mfma_f32_16x16x32_bf16(al1, bh, acc[1][nt], 0, 0, 0);
                }
            }
            __syncthreads();   // all waves done READING x from xs
            #pragma unroll
            for (int mt = 0; mt < 2; ++mt)
                #pragma unroll
                for (int nt = 0; nt < 2; ++nt) {
                    const int n = wv * 32 + nt * 16 + l15;
                    #pragma unroll
                    for (int r = 0; r < 4; ++r) {
                        const int m = mt * 16 + quad * 4 + r;
                        float v = fmaxf(acc[mt][nt][r], 0.f);
                        float rem;
                        xsh[m * XS_STRIDE + n] = f2bf_hi(v, &rem);
                        xsl[m * XS_STRIDE + n] = f2bf(rem);
                    }
                }
        }
        __syncthreads();

        // ---- layer 2: h2 = relu(hA @ W2 + b2) ----
        {
            const float* b2 = br ? wb2 : ob2;
            f32x4 acc[2][2];
            #pragma unroll
            for (int mt = 0; mt < 2; ++mt)
                #pragma unroll
                for (int nt = 0; nt < 2; ++nt) {
                    float b = b2[wv * 32 + nt * 16 + l15];
                    acc[mt][nt] = (f32x4){b, b, b, b};
                }
            const unsigned short* Wh = w2th + (size_t)br * 256 * KK2;
            const unsigned short* Wl = w2tl + (size_t)br * 256 * KK2;
            const unsigned short* a0h = xsh + l15 * XS_STRIDE + quad * 8;
            const unsigned short* a0l = xsl + l15 * XS_STRIDE + quad * 8;
            const unsigned short* a1h = a0h + 16 * XS_STRIDE;
            const unsigned short* a1l = a0l + 16 * XS_STRIDE;
            for (int k0 = 0; k0 < KK2; k0 += 32) {
                const bf16x8 ah0 = *(const bf16x8*)(a0h + k0);
                const bf16x8 al0 = *(const bf16x8*)(a0l + k0);
                const bf16x8 ah1 = *(const bf16x8*)(a1h + k0);
                const bf16x8 al1 = *(const bf16x8*)(a1l + k0);
                #pragma unroll
                for (int nt = 0; nt < 2; ++nt) {
                    const size_t n = wv * 32 + nt * 16 + l15;
                    const bf16x8 bh = *(const bf16x8*)(Wh + n * KK2 + k0 + quad * 8);
                    const bf16x8 bl = *(const bf16x8*)(Wl + n * KK2 + k0 + quad * 8);
                    acc[0][nt] = __builtin_amdgcn_mfma_f32_16x16x32_bf16(ah0, bh, acc[0][nt], 0, 0, 0);
                    acc[0][nt] = __builtin_amdgcn_mfma_f32_16x16x32_bf16(ah0, bl, acc[0][nt], 0, 0, 0);
                    acc[0][nt] = __builtin_amdgcn_mfma_f32_16x16x32_bf16(al0, bh, acc[0][nt], 0, 0, 0);
                    acc[1][nt] = __builtin_amdgcn_mfma_f32_16x16x32_bf16(ah1, bh, acc[1][nt], 0, 0, 0);
                    acc[1][nt] = __builtin_amdgcn_mfma_f32_16x16x32_bf16(ah1, bl, acc[1][nt], 0, 0, 0);
                    acc[1][nt] = __builtin_amdgcn_mfma_f32_16x16x32_bf16(al1, bh, acc[1][nt], 0, 0, 0);
                }
            }
            __syncthreads();   // all waves done READING hA from xs
            #pragma unroll
            for (int mt = 0; mt < 2; ++mt)
                #pragma unroll
                for (int nt = 0; nt < 2; ++nt) {
                    const int n = wv * 32 + nt * 16 + l15;
                    #pragma unroll
                    for (int r = 0; r < 4; ++r) {
                        const int m = mt * 16 + quad * 4 + r;
                        float v = fmaxf(acc[mt][nt][r], 0.f);
                        float rem;
                        xsh[m * XS_STRIDE + n] = f2bf_hi(v, &rem);
                        xsl[m * XS_STRIDE + n] = f2bf(rem);
                    }
                }
        }
        __syncthreads();

        // ---- layer 3: raw = h2 @ W3 + b3 (h2 read as hi+lo bf16 pair) ----
        if (br == 0) {
            const int q = t >> 4, c = t & 15;
            float s = ob3[c];
            const float4* w4 = (const float4*)(w3t + c * 256);
            const unsigned short* hrow = xsh + q * XS_STRIDE;
            const unsigned short* lrow = xsl + q * XS_STRIDE;
            for (int k = 0; k < 256; k += 8) {
                const u16x8 hi = *(const u16x8*)(hrow + k);
                const u16x8 lo = *(const u16x8*)(lrow + k);
                const float4 wa = w4[(k >> 2)];
                const float4 wb = w4[(k >> 2) + 1];
                s += (bf2f(hi[0]) + bf2f(lo[0])) * wa.x + (bf2f(hi[1]) + bf2f(lo[1])) * wa.y
                   + (bf2f(hi[2]) + bf2f(lo[2])) * wa.z + (bf2f(hi[3]) + bf2f(lo[3])) * wa.w
                   + (bf2f(hi[4]) + bf2f(lo[4])) * wb.x + (bf2f(hi[5]) + bf2f(lo[5])) * wb.y
                   + (bf2f(hi[6]) + bf2f(lo[6])) * wb.z + (bf2f(hi[7]) + bf2f(lo[7])) * wb.w;
            }
            raw[q * 24 + c] = s;
        } else if (t < TQ * 8) {
            const int q = t >> 3, c = t & 7;
            float s = wb3[c];
            const float4* w4 = (const float4*)(w3t + (16 + c) * 256);
            const unsigned short* hrow = xsh + q * XS_STRIDE;
            const unsigned short* lrow = xsl + q * XS_STRIDE;
            for (int k = 0; k < 256; k += 8) {
                const u16x8 hi = *(const u16x8*)(hrow + k);
                const u16x8 lo = *(const u16x8*)(lrow + k);
                const float4 wa = w4[(k >> 2)];
                const float4 wb = w4[(k >> 2) + 1];
                s += (bf2f(hi[0]) + bf2f(lo[0])) * wa.x + (bf2f(hi[1]) + bf2f(lo[1])) * wa.y
                   + (bf2f(hi[2]) + bf2f(lo[2])) * wa.z + (bf2f(hi[3]) + bf2f(lo[3])) * wa.w
                   + (bf2f(hi[4]) + bf2f(lo[4])) * wb.x + (bf2f(hi[5]) + bf2f(lo[5])) * wb.y
                   + (bf2f(hi[6]) + bf2f(lo[6])) * wb.z + (bf2f(hi[7]) + bf2f(lo[7])) * wb.w;
            }
            raw[q * 24 + 16 + c] = s;
        }
        __syncthreads();
    }

    // ---- epilogue: tanh, softmax, bilinear indices+weights (alias dead xs) ----
    int*   sidx = (int*)xsh;         // [TQ][8][4]
    float* sw   = (float*)xsl;       // [TQ][8][4]
    if (t < TQ) {
        const int q = t;
        float m = -1e30f;
        #pragma unroll
        for (int p = 0; p < 8; ++p) m = fmaxf(m, raw[q * 24 + 16 + p]);
        float e[8]; float S = 0.f;
        #pragma unroll
        for (int p = 0; p < 8; ++p) { e[p] = expf(raw[q * 24 + 16 + p] - m); S += e[p]; }
        float s2 = 0.f;
        #pragma unroll
        for (int p = 0; p < 8; ++p) { e[p] /= S; s2 += e[p]; }
        const float inv = 1.f / fmaxf(s2, 1e-8f);

        const float px = pcs[q * 2 + 0], py = pcs[q * 2 + 1];
        #pragma unroll
        for (int p = 0; p < 8; ++p) {
            const float cx = px + 2.f * tanhf(raw[q * 24 + 2 * p]);
            const float cy = py + 2.f * tanhf(raw[q * 24 + 2 * p + 1]);
            const float gx = fminf(fmaxf(2.f * cx * (1.f / (WW - 1)) - 1.f, -1.1f), 1.1f);
            const float gy = fminf(fmaxf(2.f * cy * (1.f / (HH - 1)) - 1.f, -1.1f), 1.1f);
            const float ix = fminf(fmaxf((gx + 1.f) * 0.5f * (WW - 1), 0.f), (float)(WW - 1));
            const float iy = fminf(fmaxf((gy + 1.f) * 0.5f * (HH - 1), 0.f), (float)(HH - 1));
            const float x0 = floorf(ix), y0 = floorf(iy);
            const float wx = ix - x0, wy = iy - y0;
            const int x0i = (int)x0, y0i = (int)y0;
            const int x1i = min(x0i + 1, WW - 1), y1i = min(y0i + 1, HH - 1);
            const float nwp = e[p] * inv;
            const int b = (q * 8 + p) * 4;
            sidx[b + 0] = (y0i * WW + x0i) * (CC / 4);
            sidx[b + 1] = (y0i * WW + x1i) * (CC / 4);
            sidx[b + 2] = (y1i * WW + x0i) * (CC / 4);
            sidx[b + 3] = (y1i * WW + x1i) * (CC / 4);
            sw[b + 0] = (1.f - wx) * (1.f - wy) * nwp;
            sw[b + 1] = wx * (1.f - wy) * nwp;
            sw[b + 2] = (1.f - wx) * wy * nwp;
            sw[b + 3] = wx * wy * nwp;
        }
    }
    __syncthreads();

    // ---- gather + weighted sum: wave wv handles q = wv*4 .. wv*4+3 ----
    const float4* fm4 = (const float4*)fmap;
    float4* out4 = (float4*)out;
    #pragma unroll
    for (int qq = 0; qq < 4; ++qq) {
        const int q = wv * 4 + qq;
        float4 acc; acc.x = acc.y = acc.z = acc.w = 0.f;
        for (int p = 0; p < 8; ++p) {
            const int b = (q * 8 + p) * 4;
            const int i00 = sidx[b + 0] + lane;
            const int i01 = sidx[b + 1] + lane;
            const int i10 = sidx[b + 2] + lane;
            const int i11 = sidx[b + 3] + lane;
            const float a00 = sw[b + 0], a01 = sw[b + 1], a10 = sw[b + 2], a11 = sw[b + 3];
            const float4 v00 = fm4[i00], v01 = fm4[i01], v10 = fm4[i10], v11 = fm4[i11];
            acc.x += a00 * v00.x + a01 * v01.x + a10 * v10.x + a11 * v11.x;
            acc.y += a00 * v00.y + a01 * v01.y + a10 * v10.y + a11 * v11.y;
            acc.z += a00 * v00.z + a01 * v01.z + a10 * v10.z + a11 * v11.z;
            acc.w += a00 * v00.w + a01 * v01.w + a10 * v10.w + a11 * v11.w;
        }
        out4[(size_t)(q0 + q) * (CC / 4) + lane] = acc;
    }
}

extern "C" void kernel_launch(void* const* d_in, const int* in_sizes, int n_in,
                              void* d_out, int out_size, void* d_ws, size_t ws_size,
                              hipStream_t stream) {
    const float* gq   = (const float*)d_in[0];
    const float* pc   = (const float*)d_in[1];
    const float* fmap = (const float*)d_in[2];
    const float* og   = (const float*)d_in[3];
    const float* obl  = (const float*)d_in[4];
    const float* oW1  = (const float*)d_in[5];
    const float* ob1  = (const float*)d_in[6];
    const float* oW2  = (const float*)d_in[7];
    const float* ob2  = (const float*)d_in[8];
    const float* oW3  = (const float*)d_in[9];
    const float* ob3  = (const float*)d_in[10];
    const float* wg   = (const float*)d_in[11];
    const float* wbl  = (const float*)d_in[12];
    const float* wW1  = (const float*)d_in[13];
    const float* wb1  = (const float*)d_in[14];
    const float* wW2  = (const float*)d_in[15];
    const float* wb2  = (const float*)d_in[16];
    const float* wW3  = (const float*)d_in[17];
    const float* wb3  = (const float*)d_in[18];

    char* ws = (char*)d_ws;
    unsigned short* w1th = (unsigned short*)(ws + WS_W1TH);
    unsigned short* w1tl = (unsigned short*)(ws + WS_W1TL);
    unsigned short* w2th = (unsigned short*)(ws + WS_W2TH);
    unsigned short* w2tl = (unsigned short*)(ws + WS_W2TL);
    float* w3t = (float*)(ws + WS_W3T);
    float* b1e = (float*)(ws + WS_B1E);
    float* out = (float*)d_out;

    prep_w1<<<dim3(KK1, 2), 256, 0, stream>>>(og, obl, oW1, ob1, wg, wbl, wW1, wb1, w1th, w1tl, b1e);
    prep_w2<<<dim3(KK2, 2), 256, 0, stream>>>(oW2, wW2, w2th, w2tl);
    prep_w3<<<2, 256, 0, stream>>>(oW3, wW3, w3t);
    fused_kernel<<<NQ / TQ, NTHR, 0, stream>>>(gq, pc, fmap, w1th, w1tl, w2th, w2tl, w3t, b1e,
                                               ob2, ob3, wb2, wb3, out);
}